// Round 7
// baseline (127.520 us; speedup 1.0000x reference)
//
#include <hip/hip_runtime.h>

// Problem constants (fixed by setup_inputs): B=4096, D=512, H=W=64, N=4096.
#define B_ROWS 4096
#define N_COLS 4096
#define DIM    512
#define LDK    1024   // row stride (elements) of split bf16 arrays [hi(512) | lo(512)]

typedef __attribute__((ext_vector_type(8))) short short8;
typedef __attribute__((ext_vector_type(4))) float floatx4;

// bf16 round-to-nearest-even split helpers (bit-exact, no API dependence)
__device__ __forceinline__ unsigned short f2bf_rn(float f) {
    unsigned u = __float_as_uint(f);
    u += 0x7fffu + ((u >> 16) & 1u);
    return (unsigned short)(u >> 16);
}
__device__ __forceinline__ float bf2f(unsigned short h) {
    return __uint_as_float(((unsigned)h) << 16);
}

// Monotone float->uint map; (key<<32)|idx gives u64 atomicMin argmin with
// smallest-index tie-break (matches numpy argmin semantics).
__device__ __forceinline__ unsigned long long pack_key(float v, int idx) {
    unsigned u = __float_as_uint(v);
    u = (u & 0x80000000u) ? ~u : (u | 0x80000000u);
    return ((unsigned long long)u << 32) | (unsigned)idx;
}

// Async global->LDS, 16B per lane. LDS dest is wave-uniform base + lane*16;
// global source address IS per-lane (m173).
__device__ __forceinline__ void async16(const unsigned short* g, unsigned short* l) {
    __builtin_amdgcn_global_load_lds(
        (__attribute__((address_space(1))) void*)g,
        (__attribute__((address_space(3))) void*)l, 16, 0, 0);
}

// One wave per row (4 rows/block): split fp32 row into bf16 hi/lo halves,
// compute exact fp32 ||row||^2, init packed argmin accumulators. (unchanged)
__global__ __launch_bounds__(256) void som_convert(
    const float* __restrict__ X, const float* __restrict__ Wt,
    unsigned short* __restrict__ Xc, unsigned short* __restrict__ Wc,
    float* __restrict__ x_sq, float* __restrict__ w_sq,
    unsigned long long* __restrict__ packed)
{
    int wave = threadIdx.x >> 6, lane = threadIdx.x & 63;
    int grow = blockIdx.x * 4 + wave;            // 0..8191
    bool isX = grow < B_ROWS;
    const float* src = isX ? (X + (size_t)grow * DIM)
                           : (Wt + (size_t)(grow - B_ROWS) * DIM);
    const float4* p4 = (const float4*)src;
    float4 a = p4[lane * 2], b = p4[lane * 2 + 1];
    float f[8] = {a.x, a.y, a.z, a.w, b.x, b.y, b.z, b.w};
    short8 hi, lo;
    float s = 0.f;
    #pragma unroll
    for (int t = 0; t < 8; ++t) {
        unsigned short h = f2bf_rn(f[t]);
        hi[t] = (short)h;
        lo[t] = (short)f2bf_rn(f[t] - bf2f(h));
        s = fmaf(f[t], f[t], s);
    }
    unsigned short* dst = (isX ? Xc + (size_t)grow * LDK
                               : Wc + (size_t)(grow - B_ROWS) * LDK) + lane * 8;
    *(short8*)(dst)       = hi;
    *(short8*)(dst + 512) = lo;
    #pragma unroll
    for (int off = 32; off >= 1; off >>= 1) s += __shfl_xor(s, off, 64);
    if (lane == 0) {
        if (isX) { x_sq[grow] = s; packed[grow] = ~0ull; }
        else     { w_sq[grow - B_ROWS] = s; }
    }
}

// ---------------------------------------------------------------------------
// Split-bf16 distance GEMM v8 = v7 (128x128 tile, 4 waves 2x2, BK=32,
// granule-rotation conflict-free LDS, coalesced staging, default block map)
// + 64KB LDS DOUBLE BUFFER at 2 blocks/CU + counted vmcnt (T4):
//   per K-step: vmcnt(8) gate (tile kt ready; kt+1's 8 loads stay in
//   flight) -> barrier -> read ah,bh -> 16 MFMA -> read bl,al -> lgkm0 +
//   barrier (read-done) -> stage tile kt+2 into buf[cur] -> 32 MFMA.
//   vmcnt never drains to 0 in the main loop; staged loads get ~80 MFMAs
//   of cover (clusters 2-3 of kt + all of kt+1) before their gate.
//   Each wave gates its OWN loads; the barrier broadcasts readiness
//   (all waves' slices done) — the proven v3/v5 pattern.
// Cross-block hiding retained: 64KB -> 2 blocks/CU (v2-v5's 1-block
// regression avoided). Per-acc product order identical to v1 (hh, ah*bl,
// al*bh; k ascending) => bit-exact.
// LDS map per buffer (shorts): Ah @0, Al @4096, Bh @8192, Bl @12288;
// each array = 8 subtiles (16 rows x 32 elems, 1KB) in rotation layout:
// granule (r,g) at word 4r + ((g + ((r>>1)&3)) & 3).
// ---------------------------------------------------------------------------
__global__ __launch_bounds__(256, 2) void som_dist_v8(
    const unsigned short* __restrict__ Xc, const unsigned short* __restrict__ Wc,
    const float* __restrict__ w_sq, unsigned long long* __restrict__ packed)
{
    __shared__ __align__(16) unsigned short L[2 * 16384];   // 2 x 32 KiB
    const int tid  = threadIdx.x;
    const int wave = tid >> 6, lane = tid & 63;
    const int wr = wave >> 1, wc = wave & 1;       // 2x2 wave grid
    const int bm = blockIdx.y, bn = blockIdx.x;
    const int quad = lane >> 4, t16 = lane & 15;

    // Staging: wave stages rows [wave*32, wave*32+32) of all four arrays,
    // 8 async16/K-step. Rotated chunk keeps 64B-segment coalescing while
    // matching the swizzled LDS image (v7-proven).
    const int srow = lane >> 2;                            // 0..15
    const int scol = ((((lane & 3) - ((lane >> 3) & 3)) & 3)) * 8;
    const unsigned short* gAh = Xc + (size_t)(bm * 128 + wave * 32 + srow) * LDK + scol;
    const unsigned short* gBh = Wc + (size_t)(bn * 128 + wave * 32 + srow) * LDK + scol;
    const unsigned short* gAl = gAh + 512;
    const unsigned short* gBl = gBh + 512;
    const int wofs = wave * 1024;   // this wave's 2-subtile slice within an array

    // Fragment read offset: word within subtile for (row t16, chunk quad).
    const int rdw = 4 * t16 + ((quad + ((t16 >> 1) & 3)) & 3);
    const int ra = wr * 2048 + rdw * 8;          // within Ah/Al region
    const int rb = 8192 + wc * 2048 + rdw * 8;   // within Bh/Bl region

    floatx4 acc[4][4];
    #pragma unroll
    for (int i = 0; i < 4; ++i)
        #pragma unroll
        for (int j = 0; j < 4; ++j) acc[i][j] = (floatx4){0.f, 0.f, 0.f, 0.f};

    // Prologue: stage tile 0 -> buf0, tile 1 -> buf1 (16 loads in flight).
    #pragma unroll
    for (int b = 0; b < 2; ++b) {
        unsigned short* base = &L[b * 16384];
        const int k0 = b * 32;
        async16(gAh + k0,            base + wofs);
        async16(gAh + k0 + 16 * LDK, base + wofs + 512);
        async16(gAl + k0,            base + 4096 + wofs);
        async16(gAl + k0 + 16 * LDK, base + 4096 + wofs + 512);
        async16(gBh + k0,            base + 8192 + wofs);
        async16(gBh + k0 + 16 * LDK, base + 8192 + wofs + 512);
        async16(gBl + k0,            base + 12288 + wofs);
        async16(gBl + k0 + 16 * LDK, base + 12288 + wofs + 512);
    }

    #pragma unroll 1
    for (int kt = 0; kt < 16; ++kt) {
        const int cur = kt & 1;
        unsigned short* base = &L[cur * 16384];

        // GATE: this wave's tile-kt loads done; tile kt+1's 8 stay in flight.
        // Barrier: every wave passed its own gate => all slices of kt ready.
        if (kt == 15) asm volatile("s_waitcnt vmcnt(0)" ::: "memory");
        else          asm volatile("s_waitcnt vmcnt(8)" ::: "memory");
        __builtin_amdgcn_s_barrier();

        short8 ah[4], bh[4], bl[4], al[4];
        #pragma unroll
        for (int i = 0; i < 4; ++i) ah[i] = *(const short8*)(base + ra + i * 512);
        #pragma unroll
        for (int j = 0; j < 4; ++j) bh[j] = *(const short8*)(base + rb + j * 512);

        __builtin_amdgcn_s_setprio(1);
        #pragma unroll
        for (int i = 0; i < 4; ++i)
            #pragma unroll
            for (int j = 0; j < 4; ++j)
                acc[i][j] = __builtin_amdgcn_mfma_f32_16x16x32_bf16(
                    ah[i], bh[j], acc[i][j], 0, 0, 0);
        __builtin_amdgcn_s_setprio(0);

        #pragma unroll
        for (int j = 0; j < 4; ++j) bl[j] = *(const short8*)(base + rb + 4096 + j * 512);
        #pragma unroll
        for (int i = 0; i < 4; ++i) al[i] = *(const short8*)(base + ra + 4096 + i * 512);

        // READ-DONE: all of this wave's ds_reads of buf[cur] retired; after
        // the barrier every wave is done => tile kt+2 may overwrite buf[cur].
        asm volatile("s_waitcnt lgkmcnt(0)" ::: "memory");
        __builtin_amdgcn_s_barrier();

        if (kt < 14) {
            const int k0 = (kt + 2) * 32;
            async16(gAh + k0,            base + wofs);
            async16(gAh + k0 + 16 * LDK, base + wofs + 512);
            async16(gAl + k0,            base + 4096 + wofs);
            async16(gAl + k0 + 16 * LDK, base + 4096 + wofs + 512);
            async16(gBh + k0,            base + 8192 + wofs);
            async16(gBh + k0 + 16 * LDK, base + 8192 + wofs + 512);
            async16(gBl + k0,            base + 12288 + wofs);
            async16(gBl + k0 + 16 * LDK, base + 12288 + wofs + 512);
        }

        __builtin_amdgcn_s_setprio(1);
        #pragma unroll
        for (int i = 0; i < 4; ++i)
            #pragma unroll
            for (int j = 0; j < 4; ++j)
                acc[i][j] = __builtin_amdgcn_mfma_f32_16x16x32_bf16(
                    ah[i], bl[j], acc[i][j], 0, 0, 0);
        #pragma unroll
        for (int i = 0; i < 4; ++i)
            #pragma unroll
            for (int j = 0; j < 4; ++j)
                acc[i][j] = __builtin_amdgcn_mfma_f32_16x16x32_bf16(
                    al[i], bh[j], acc[i][j], 0, 0, 0);
        __builtin_amdgcn_s_setprio(0);
    }

    // Epilogue: val = w_sq - 2*dot (x_sq is per-row constant, irrelevant to
    // argmin). C/D layout: col = t16, row = quad*4 + reg  [m89/m91].
    const int col0 = bn * 128 + wc * 64 + t16;
    float wq[4];
    #pragma unroll
    for (int j = 0; j < 4; ++j) wq[j] = w_sq[col0 + j * 16];
    const int row_base = bm * 128 + wr * 64 + quad * 4;
    #pragma unroll
    for (int i = 0; i < 4; ++i) {
        #pragma unroll
        for (int r = 0; r < 4; ++r) {
            unsigned long long best = ~0ull;
            #pragma unroll
            for (int j = 0; j < 4; ++j) {
                float val = fmaf(-2.f, acc[i][j][r], wq[j]);
                unsigned long long key = pack_key(val, col0 + j * 16);
                best = (key < best) ? key : best;
            }
            #pragma unroll
            for (int m = 1; m <= 8; m <<= 1) {     // reduce 16-lane col group
                unsigned long long o = __shfl_xor(best, m, 64);
                best = (o < best) ? o : best;
            }
            if (t16 == 0)
                atomicMin(&packed[row_base + i * 16 + r], best);
        }
    }
}

// Unpack argmin, qe = sqrt(max(||x||^2 + val, 0)).
// d_out: bmu_indices (4096 x 2) flat, then qe (4096), all float. (unchanged)
__global__ __launch_bounds__(256) void som_finalize(
    const unsigned long long* __restrict__ packed,
    const float* __restrict__ x_sq, float* __restrict__ out)
{
    int b = blockIdx.x * 256 + threadIdx.x;  // 0..4095
    unsigned long long p = packed[b];
    unsigned idx = (unsigned)(p & 0xffffffffull);
    unsigned key = (unsigned)(p >> 32);
    unsigned u = (key & 0x80000000u) ? (key & 0x7fffffffu) : ~key;
    float val = __uint_as_float(u);
    float sq = fmaxf(x_sq[b] + val, 0.f);
    out[2 * b]     = (float)(idx >> 6);   // y = idx / 64
    out[2 * b + 1] = (float)(idx & 63);   // x = idx % 64
    out[2 * B_ROWS + b] = sqrtf(sq);
}

extern "C" void kernel_launch(void* const* d_in, const int* in_sizes, int n_in,
                              void* d_out, int out_size, void* d_ws, size_t ws_size,
                              hipStream_t stream) {
    const float* X  = (const float*)d_in[0];   // (4096, 512)
    const float* Wt = (const float*)d_in[1];   // (64, 64, 512) -> (4096, 512)
    float* out = (float*)d_out;

    // ws layout: [0,32K) packed u64[4096]; [32K,48K) x_sq; [48K,64K) w_sq;
    // [64K, 64K+8M) Xc bf16 split; [64K+8M, 64K+16M) Wc bf16 split.
    unsigned long long* packed = (unsigned long long*)d_ws;
    float* x_sq = (float*)((char*)d_ws + (32 << 10));
    float* w_sq = (float*)((char*)d_ws + (48 << 10));
    unsigned short* Xc = (unsigned short*)((char*)d_ws + (64 << 10));
    unsigned short* Wc = (unsigned short*)((char*)d_ws + (64 << 10) + ((size_t)B_ROWS * LDK * 2));

    som_convert<<<dim3((B_ROWS + N_COLS) / 4), dim3(256), 0, stream>>>(
        X, Wt, Xc, Wc, x_sq, w_sq, packed);
    som_dist_v8<<<dim3(N_COLS / 128, B_ROWS / 128), dim3(256), 0, stream>>>(
        Xc, Wc, w_sq, packed);
    som_finalize<<<dim3(B_ROWS / 256), dim3(256), 0, stream>>>(packed, x_sq, out);
}